// Round 3
// baseline (268.572 us; speedup 1.0000x reference)
//
#include <hip/hip_runtime.h>

typedef short short8 __attribute__((ext_vector_type(8)));
typedef float floatx4 __attribute__((ext_vector_type(4)));

#define HEAD 256
#define CDIM 1024
#define TT   2048

// ws layout (u16 elements)
#define WT_EL    0              // 768*1024 = 786432
#define FLAG_EL  786432         // int flag (2 u16 slots), pad to 786560
#define QW_EL    786560
#define KW_EL    (QW_EL + 4194304)
#define VW_EL    (KW_EL + 4194304)
#define XC_EL    (VW_EL + 4194304)   // x copy 16777216 el
#define NEED_FULL_BYTES ((size_t)(XC_EL + 16777216) * 2)   // ~60.3 MB

static __device__ __forceinline__ unsigned short f2bf(float f) {
    unsigned int u = __builtin_bit_cast(unsigned int, f);
    u += 0x7FFFu + ((u >> 16) & 1u);   // round-to-nearest-even
    return (unsigned short)(u >> 16);
}

// ---------------------------------------------------------------------------
// dtype probe: Wq ~ U(-1/32,1/32). f32 storage reinterpreted as u16 halves has
// random low-half exponents -> some half has exp>=128 w.p. ~1-2^-256.
// bf16 storage (max |Wq| < 0.04, exp<=122) never triggers. flag: 1=f32, 0=bf16.
// ---------------------------------------------------------------------------
__global__ void detect_kernel(const unsigned short* __restrict__ Wq, int* flag) {
    int lane = threadIdx.x;
    int bad = 0;
    for (int i = lane; i < 512; i += 64) {
        unsigned int e = (Wq[i] >> 7) & 0xFF;
        bad |= (e >= 128) ? 1 : 0;
    }
#pragma unroll
    for (int off = 1; off < 64; off <<= 1) bad |= __shfl_xor(bad, off);
    if (lane == 0) *flag = bad;
}

// ---------------------------------------------------------------------------
// x -> canonical bf16 buffer. grid 8192 x 256, 8 elements/thread.
// ---------------------------------------------------------------------------
__global__ __launch_bounds__(256) void convert_x(
    const void* __restrict__ src, unsigned short* __restrict__ dst,
    const int* __restrict__ flagp) {
    int f = *flagp;
    size_t i = ((size_t)blockIdx.x * 256 + threadIdx.x) * 8;
    if (f) {
        const float* s = (const float*)src;
        short8 o;
#pragma unroll
        for (int j = 0; j < 8; j++) o[j] = (short)f2bf(s[i + j]);
        *(short8*)&dst[i] = o;
    } else {
        *(short8*)&dst[i] = *(const short8*)((const unsigned short*)src + i);
    }
}

// ---------------------------------------------------------------------------
// weights transpose+concat: Wt[n][k] = W_{n>>8}[k][n&255], dtype per flag.
// grid (32, 24), block (32, 8).
// ---------------------------------------------------------------------------
__global__ __launch_bounds__(256) void wt_kernel(
    const void* __restrict__ Wq, const void* __restrict__ Wk,
    const void* __restrict__ Wv, unsigned short* __restrict__ Wt,
    const int* __restrict__ flagp, int mode) {
    int f = (mode < 0) ? *flagp : mode;
    __shared__ unsigned short tile[32][33];
    int k0 = blockIdx.x * 32;
    int n0 = blockIdx.y * 32;
    const void* W = (n0 < 256) ? Wq : (n0 < 512) ? Wk : Wv;
    int c0 = n0 & 255;
    int tx = threadIdx.x, ty = threadIdx.y;
#pragma unroll
    for (int i = 0; i < 4; i++) {
        int r = ty + 8 * i;
        size_t idx = (size_t)(k0 + r) * HEAD + c0 + tx;
        tile[r][tx] = f ? f2bf(((const float*)W)[idx])
                        : ((const unsigned short*)W)[idx];
    }
    __syncthreads();
#pragma unroll
    for (int i = 0; i < 4; i++) {
        int rn = ty + 8 * i;
        Wt[(size_t)(n0 + rn) * CDIM + k0 + tx] = tile[tx][rn];
    }
}

// ---------------------------------------------------------------------------
// QKV GEMM: [16384,768] = X[16384,1024] @ Wt^T. 128x128 tile, 4 waves.
// grid (6, 128), block 256.
// ---------------------------------------------------------------------------
__global__ __launch_bounds__(256) void gemm_qkv(
    const unsigned short* __restrict__ X,
    const unsigned short* __restrict__ Wt,
    unsigned short* __restrict__ Q,
    unsigned short* __restrict__ K,
    unsigned short* __restrict__ V) {
    __shared__ __attribute__((aligned(16))) short As[128 * 40];
    __shared__ __attribute__((aligned(16))) short Bs[128 * 40];

    int tid  = threadIdx.x;
    int wave = tid >> 6, lane = tid & 63, quad = lane >> 4, lq = lane & 15;
    int wm = wave >> 1, wn = wave & 1;
    int m0  = blockIdx.y * 128;
    int n0b = blockIdx.x * 128;

    floatx4 acc[4][4];
#pragma unroll
    for (int i = 0; i < 4; i++)
#pragma unroll
        for (int j = 0; j < 4; j++)
#pragma unroll
            for (int r = 0; r < 4; r++) acc[i][j][r] = 0.f;

    for (int kt = 0; kt < 32; kt++) {
        int k0 = kt * 32;
        __syncthreads();
#pragma unroll
        for (int g = 0; g < 2; g++) {
            int seg = g * 256 + tid;
            int row = seg >> 2, c8 = (seg & 3) * 8;
            *(short8*)&As[row * 40 + c8] =
                *(const short8*)&X[(size_t)(m0 + row) * CDIM + k0 + c8];
            *(short8*)&Bs[row * 40 + c8] =
                *(const short8*)&Wt[(size_t)(n0b + row) * CDIM + k0 + c8];
        }
        __syncthreads();
        short8 af[4], bfv[4];
#pragma unroll
        for (int i = 0; i < 4; i++)
            af[i] = *(short8*)&As[(64 * wm + 16 * i + lq) * 40 + quad * 8];
#pragma unroll
        for (int j = 0; j < 4; j++)
            bfv[j] = *(short8*)&Bs[(64 * wn + 16 * j + lq) * 40 + quad * 8];
#pragma unroll
        for (int i = 0; i < 4; i++)
#pragma unroll
            for (int j = 0; j < 4; j++)
                acc[i][j] = __builtin_amdgcn_mfma_f32_16x16x32_bf16(
                    af[i], bfv[j], acc[i][j], 0, 0, 0);
    }

    int sel = n0b >> 8;
    unsigned short* outp = (sel == 0) ? Q : (sel == 1) ? K : V;
    float scale = (sel == 0) ? 0.0625f : 1.0f;   // fold 1/sqrt(256) into Q
    int cbase = n0b & 255;
#pragma unroll
    for (int i = 0; i < 4; i++)
#pragma unroll
        for (int j = 0; j < 4; j++)
#pragma unroll
            for (int r = 0; r < 4; r++) {
                int rr = m0 + 64 * wm + 16 * i + quad * 4 + r;
                int cc = cbase + 64 * wn + 16 * j + lq;
                outp[(size_t)rr * HEAD + cc] = f2bf(acc[i][j][r] * scale);
            }
}

// ---------------------------------------------------------------------------
// flash attention (causal). grid (32 q-tiles, 8 batches), block 256.
// OUTPUT IS FLOAT32 (reference output dtype).
// ---------------------------------------------------------------------------
__global__ __launch_bounds__(256) void attn(
    const unsigned short* __restrict__ Q,
    const unsigned short* __restrict__ K,
    const unsigned short* __restrict__ V,
    float* __restrict__ out) {
    __shared__ __attribute__((aligned(16))) short Ks[64 * 264];
    __shared__ __attribute__((aligned(16))) short Vt[256 * 72];
    __shared__ __attribute__((aligned(16))) short Ps[64 * 72];

    int tid  = threadIdx.x;
    int wave = tid >> 6, lane = tid & 63, quad = lane >> 4, lq = lane & 15;
    int bq = blockIdx.x;
    int b  = blockIdx.y;
    int q0 = bq * 64;
    size_t boff = (size_t)b * TT * HEAD;
    const unsigned short* Qb = Q + boff;
    const unsigned short* Kb = K + boff;
    const unsigned short* Vb = V + boff;

    short8 qf[8];
    int qrow = q0 + 16 * wave + lq;
#pragma unroll
    for (int kk = 0; kk < 8; kk++)
        qf[kk] = *(const short8*)&Qb[(size_t)qrow * HEAD + kk * 32 + quad * 8];

    float m_i[4], l_i[4];
    floatx4 accO[16];
#pragma unroll
    for (int r = 0; r < 4; r++) { m_i[r] = -1e30f; l_i[r] = 0.f; }
#pragma unroll
    for (int n = 0; n < 16; n++)
#pragma unroll
        for (int r = 0; r < 4; r++) accO[n][r] = 0.f;

    int vs = tid & 63, dblk = tid >> 6;

    int nt = bq + 1;
    for (int it = 0; it < nt; it++) {
        int s0 = it * 64;
        __syncthreads();
#pragma unroll
        for (int g = 0; g < 8; g++) {
            int seg = g * 256 + tid;
            int row = seg >> 5, c8 = (seg & 31) * 8;
            *(short8*)&Ks[row * 264 + c8] =
                *(const short8*)&Kb[(size_t)(s0 + row) * HEAD + c8];
        }
#pragma unroll
        for (int g = 0; g < 8; g++) {
            int d0 = dblk * 64 + g * 8;
            short8 vv = *(const short8*)&Vb[(size_t)(s0 + vs) * HEAD + d0];
#pragma unroll
            for (int i2 = 0; i2 < 8; i2++)
                Vt[(d0 + i2) * 72 + vs] = vv[i2];
        }
        __syncthreads();

        floatx4 accS[4];
#pragma unroll
        for (int n = 0; n < 4; n++)
#pragma unroll
            for (int r = 0; r < 4; r++) accS[n][r] = 0.f;
#pragma unroll
        for (int kk = 0; kk < 8; kk++) {
            short8 a = qf[kk];
#pragma unroll
            for (int n = 0; n < 4; n++) {
                short8 bk = *(short8*)&Ks[(16 * n + lq) * 264 + kk * 32 + quad * 8];
                accS[n] = __builtin_amdgcn_mfma_f32_16x16x32_bf16(a, bk, accS[n], 0, 0, 0);
            }
        }

        if (it == nt - 1) {
#pragma unroll
            for (int n = 0; n < 4; n++) {
                int sg = s0 + 16 * n + lq;
#pragma unroll
                for (int r = 0; r < 4; r++) {
                    int qg = q0 + 16 * wave + quad * 4 + r;
                    if (sg > qg) accS[n][r] = -1e30f;
                }
            }
        }

        float p[4][4], alpha[4];
#pragma unroll
        for (int r = 0; r < 4; r++) {
            float rm = accS[0][r];
#pragma unroll
            for (int n = 1; n < 4; n++) rm = fmaxf(rm, accS[n][r]);
#pragma unroll
            for (int off = 1; off < 16; off <<= 1)
                rm = fmaxf(rm, __shfl_xor(rm, off));
            float mn = fmaxf(m_i[r], rm);
            alpha[r] = __expf(m_i[r] - mn);
            m_i[r] = mn;
            float rs = 0.f;
#pragma unroll
            for (int n = 0; n < 4; n++) {
                float pv = __expf(accS[n][r] - mn);
                p[n][r] = pv;
                rs += pv;
            }
#pragma unroll
            for (int off = 1; off < 16; off <<= 1)
                rs += __shfl_xor(rs, off);
            l_i[r] = l_i[r] * alpha[r] + rs;
        }
#pragma unroll
        for (int n = 0; n < 16; n++)
#pragma unroll
            for (int r = 0; r < 4; r++) accO[n][r] *= alpha[r];

#pragma unroll
        for (int r = 0; r < 4; r++)
#pragma unroll
            for (int n = 0; n < 4; n++)
                Ps[(16 * wave + quad * 4 + r) * 72 + 16 * n + lq] =
                    (short)f2bf(p[n][r]);

#pragma unroll
        for (int kk = 0; kk < 2; kk++) {
            short8 ap = *(short8*)&Ps[(16 * wave + lq) * 72 + kk * 32 + quad * 8];
#pragma unroll
            for (int n = 0; n < 16; n++) {
                short8 bv = *(short8*)&Vt[(16 * n + lq) * 72 + kk * 32 + quad * 8];
                accO[n] = __builtin_amdgcn_mfma_f32_16x16x32_bf16(ap, bv, accO[n], 0, 0, 0);
            }
        }
    }

    // epilogue: O / l, written as FLOAT32
    float* ob = out + boff;
#pragma unroll
    for (int r = 0; r < 4; r++) {
        float inv = 1.0f / l_i[r];
        int rr = q0 + 16 * wave + quad * 4 + r;
#pragma unroll
        for (int n = 0; n < 16; n++)
            ob[(size_t)rr * HEAD + 16 * n + lq] = accO[n][r] * inv;
    }
}

// ---------------------------------------------------------------------------
extern "C" void kernel_launch(void* const* d_in, const int* in_sizes, int n_in,
                              void* d_out, int out_size, void* d_ws, size_t ws_size,
                              hipStream_t stream) {
    const void* x  = d_in[0];
    const void* Wq = d_in[1];
    const void* Wk = d_in[2];
    const void* Wv = d_in[3];
    unsigned short* ws = (unsigned short*)d_ws;

    unsigned short* Wt = ws + WT_EL;
    int*            flagp = (int*)(ws + FLAG_EL);
    unsigned short* Qw = ws + QW_EL;
    unsigned short* Kw = ws + KW_EL;
    unsigned short* Vw = ws + VW_EL;
    unsigned short* xc = ws + XC_EL;
    float* outp = (float*)d_out;

    bool full = (ws_size >= NEED_FULL_BYTES);

    const unsigned short* Xp;
    if (full) {
        detect_kernel<<<1, 64, 0, stream>>>((const unsigned short*)Wq, flagp);
        convert_x<<<8192, 256, 0, stream>>>(x, xc, flagp);
        wt_kernel<<<dim3(32, 24), dim3(32, 8), 0, stream>>>(Wq, Wk, Wv, Wt, flagp, -1);
        Xp = xc;
    } else {
        wt_kernel<<<dim3(32, 24), dim3(32, 8), 0, stream>>>(Wq, Wk, Wv, Wt, flagp, 0);
        Xp = (const unsigned short*)x;
    }

    gemm_qkv<<<dim3(6, 128), 256, 0, stream>>>(Xp, Wt, Qw, Kw, Vw);
    attn<<<dim3(32, 8), 256, 0, stream>>>(Qw, Kw, Vw, outp);
}